// Round 4
// baseline (407.559 us; speedup 1.0000x reference)
//
#include <hip/hip_runtime.h>
#include <hip/hip_bf16.h>

#define Mm 256
#define Tt 64
#define DM 512     // D_MOT == fc1-in == 2*M == D_ABS
#define DO 768
#define OUT_TILE ((size_t)Mm * DO)

// ---------------------------------------------------------------------------
// G[m,k] = b2[k] + sum_j b1[j]*W2[j,k] + sum_j pos[m,j]*W2[DM+j,k]
// grid: 64 m-groups (4 rows) x 4 k-slices (192 cols); block 192
// TO_OUT=0: write G to ws.  TO_OUT=1: broadcast G to every tile of out (fallback).
template <int TO_OUT>
__global__ void k_G(const float* __restrict__ pos, const float* __restrict__ w2,
                    const float* __restrict__ b1, const float* __restrict__ b2,
                    float* __restrict__ Gws, float* __restrict__ outg) {
    __shared__ float posT[DM * 4];  // posT[j*4+mi]
    __shared__ float b1s[DM];
    int mg = blockIdx.x >> 2, ks = blockIdx.x & 3;
    int t = threadIdx.x;
    for (int idx = t; idx < DM * 4; idx += 192)
        posT[idx] = pos[(mg * 4 + (idx & 3)) * DM + (idx >> 2)];
    for (int idx = t; idx < DM; idx += 192) b1s[idx] = b1[idx];
    __syncthreads();
    int k = ks * 192 + t;
    float pb = b2[k];
#pragma unroll 4
    for (int j = 0; j < DM; ++j) pb += b1s[j] * w2[j * DO + k];
    float a0 = pb, a1 = pb, a2 = pb, a3 = pb;
#pragma unroll 4
    for (int j = 0; j < DM; ++j) {
        float w = w2[(DM + j) * DO + k];
        float4 q = *(const float4*)&posT[j * 4];
        a0 += q.x * w; a1 += q.y * w; a2 += q.z * w; a3 += q.w * w;
    }
    if (TO_OUT) {
        for (int tile = 0; tile < 256; ++tile) {
            size_t base = (size_t)tile * OUT_TILE + (size_t)(mg * 4) * DO + k;
            outg[base + 0 * DO] = a0;
            outg[base + 1 * DO] = a1;
            outg[base + 2 * DO] = a2;
            outg[base + 3 * DO] = a3;
        }
    } else {
        Gws[(mg * 4 + 0) * DO + k] = a0;
        Gws[(mg * 4 + 1) * DO + k] = a1;
        Gws[(mg * 4 + 2) * DO + k] = a2;
        Gws[(mg * 4 + 3) * DO + k] = a3;
    }
}

// ---------------------------------------------------------------------------
// One block per tile (b,t). Phase 1: stage (v*c0, v*c1, v) per m in LDS.
// Phase 2 (threads 0..511): S0[j]=sum_n v_n W1[2n,j], S1[j]=sum_n v_n W1[2n+1,j],
//                           U[j]=sum_n v_n(c_n0 W1[2n,j]+c_n1 W1[2n+1,j]).
// Phase 3 (all 768 threads, one k each): P0/P1/PU = S @ W2_top column k.
// Epilogue: out[m,k] = G[m,k] + v_m c_m0 P0 + v_m c_m1 P1 - v_m PU  (fp32 store).
// G_FROM_OUT=0: G read from ws.  =1: G read from out (RMW fallback).
template <int G_FROM_OUT>
__global__ void k_main(const float* __restrict__ coords, const float* __restrict__ vis,
                       const float* __restrict__ w1, const float* __restrict__ w2,
                       const float* __restrict__ Gws, float* __restrict__ out) {
    __shared__ float4 abc[Mm];  // (v*c0, v*c1, v, 0) per m
    __shared__ float s0s[DM], s1s[DM], uus[DM];
    int tile = blockIdx.x;
    int b = tile >> 6, tt = tile & 63;
    int t = threadIdx.x;
    if (t < Mm) {
        int m = t;
        float2 c = *(const float2*)&coords[((size_t)(b * Mm + m) * Tt + tt) * 2];
        float v = vis[(b * Mm + m) * Tt + tt];
        float c0 = c.x, c1 = c.y;
        if (isnan(c0)) { v = 0.f; c0 = 0.f; }
        if (isnan(c1)) c1 = 0.f;
        abc[m] = make_float4(v * c0, v * c1, v, 0.f);
    }
    __syncthreads();
    if (t < DM) {
        int j = t;
        float s0 = 0.f, s1 = 0.f, uu = 0.f;
#pragma unroll 4
        for (int n = 0; n < Mm; ++n) {
            float4 a = abc[n];
            float w0 = w1[(2 * n) * DM + j];
            float wv = w1[(2 * n + 1) * DM + j];
            s0 += a.z * w0;
            s1 += a.z * wv;
            uu += a.x * w0 + a.y * wv;
        }
        s0s[j] = s0; s1s[j] = s1; uus[j] = uu;
    }
    __syncthreads();
    int k = t;  // block = 768
    float p0 = 0.f, p1 = 0.f, pu = 0.f;
#pragma unroll 4
    for (int j = 0; j < DM; ++j) {
        float w = w2[j * DO + k];
        p0 += s0s[j] * w; p1 += s1s[j] * w; pu += uus[j] * w;
    }
    size_t ob = (size_t)tile * OUT_TILE + k;
#pragma unroll 2
    for (int m = 0; m < Mm; ++m) {
        float4 a = abc[m];
        float g = G_FROM_OUT ? out[ob + (size_t)m * DO] : Gws[m * DO + k];
        out[ob + (size_t)m * DO] = g + a.x * p0 + a.y * p1 - a.z * pu;
    }
}

// ---------------------------------------------------------------------------
extern "C" void kernel_launch(void* const* d_in, const int* in_sizes, int n_in,
                              void* d_out, int out_size, void* d_ws, size_t ws_size,
                              hipStream_t stream) {
    const float* coords = (const float*)d_in[0];
    const float* vis    = (const float*)d_in[1];
    const float* pos    = (const float*)d_in[2];
    const float* w1     = (const float*)d_in[3];
    const float* b1     = (const float*)d_in[4];
    const float* w2     = (const float*)d_in[5];
    const float* b2     = (const float*)d_in[6];
    float* out = (float*)d_out;   // reference output dtype = float32
    float* Gws = (float*)d_ws;

    // Scratch need: G = 256*768 fp32 = 786,432 bytes. Branch is constant per
    // deployment (ws_size fixed) -> graph-capture safe.
    if (ws_size >= (size_t)Mm * DO * sizeof(float)) {
        k_G<0>   <<<dim3(256), dim3(192), 0, stream>>>(pos, w2, b1, b2, Gws, nullptr);
        k_main<0><<<dim3(256), dim3(768), 0, stream>>>(coords, vis, w1, w2, Gws, out);
    } else {
        // Zero-scratch fallback: broadcast G into out, then RMW.
        k_G<1>   <<<dim3(256), dim3(192), 0, stream>>>(pos, w2, b1, b2, nullptr, out);
        k_main<1><<<dim3(256), dim3(768), 0, stream>>>(coords, vis, w1, w2, nullptr, out);
    }
}

// Round 5
// 314.115 us; speedup vs baseline: 1.2975x; 1.2975x over previous
//
#include <hip/hip_runtime.h>
#include <hip/hip_bf16.h>

#define Mm 256
#define Tt 64
#define DM 512     // D_MOT == fc1-in == 2*M == D_ABS
#define DO 768
#define OUT_TILE ((size_t)Mm * DO)

// ============================ FAST PATH =====================================
// ws layout (floats): [Q 513*768][G 256*768]   (2.36 MB)
#define Q_ROWS 513
#define WS_G ((size_t)Q_ROWS * DO)

// ---------------------------------------------------------------------------
// One tiled GEMM kernel, two variants by blockIdx.y:
//   rt 0..8  (Q): C[r,k] = sum_j A[r,j] * w2[j,k],  A = [W1 (512 rows); b1 (row 512)]
//   rt 9..12 (G): C[r,k] = sum_j pos[r,j] * w2[512+j,k]
// 64x64 C-tile per block, 256 threads, 4x4 micro-tile, K staged in LDS (16).
__global__ __launch_bounds__(256) void k_gemm(
    const float* __restrict__ w1, const float* __restrict__ b1,
    const float* __restrict__ pos, const float* __restrict__ w2,
    float* __restrict__ Qws, float* __restrict__ Gws) {
    __shared__ float As[16][64];
    __shared__ float Bs[16][64];
    int ct = blockIdx.x;            // 0..11
    int rt = blockIdx.y;            // 0..12
    bool isQ = rt < 9;
    int m0 = isQ ? rt * 64 : (rt - 9) * 64;
    int c0 = ct * 64;
    const float* Bp = isQ ? w2 : w2 + (size_t)DM * DO;
    int t = threadIdx.x;
    int tx = t & 15, ty = t >> 4;
    int mm = t & 63, kb = t >> 6;   // loader coords
    float acc[4][4] = {};
    for (int ks = 0; ks < DM; ks += 16) {
#pragma unroll
        for (int i = 0; i < 4; ++i) {
            int kk = kb + 4 * i;
            int j = ks + kk;
            int rr = m0 + mm;
            float av;
            if (isQ) av = (rr < 512) ? w1[rr * DM + j] : (rr == 512 ? b1[j] : 0.f);
            else     av = pos[rr * DM + j];
            As[kk][mm] = av;
            Bs[kk][mm] = Bp[(size_t)j * DO + c0 + mm];
        }
        __syncthreads();
#pragma unroll
        for (int kk = 0; kk < 16; ++kk) {
            float4 a = *(const float4*)&As[kk][ty * 4];
            float4 b = *(const float4*)&Bs[kk][tx * 4];
            acc[0][0] += a.x * b.x; acc[0][1] += a.x * b.y; acc[0][2] += a.x * b.z; acc[0][3] += a.x * b.w;
            acc[1][0] += a.y * b.x; acc[1][1] += a.y * b.y; acc[1][2] += a.y * b.z; acc[1][3] += a.y * b.w;
            acc[2][0] += a.z * b.x; acc[2][1] += a.z * b.y; acc[2][2] += a.z * b.z; acc[2][3] += a.z * b.w;
            acc[3][0] += a.w * b.x; acc[3][1] += a.w * b.y; acc[3][2] += a.w * b.z; acc[3][3] += a.w * b.w;
        }
        __syncthreads();
    }
    float* C = isQ ? Qws : Gws;
#pragma unroll
    for (int i = 0; i < 4; ++i) {
        int r = m0 + ty * 4 + i;
        if (isQ && r > 512) continue;    // Q has 513 valid rows
        float4 v = make_float4(acc[i][0], acc[i][1], acc[i][2], acc[i][3]);
        *(float4*)&C[(size_t)r * DO + c0 + tx * 4] = v;
    }
}

// ---------------------------------------------------------------------------
// grid: 256 tiles x 2 k-halves; block 384 (one k per thread).
// P0/P1/PU from Q (L2-resident), then stream out = G + pq + a.x*P0 + a.y*P1 - a.z*PU
__global__ __launch_bounds__(384) void k_epi(
    const float* __restrict__ coords, const float* __restrict__ vis,
    const float* __restrict__ Qws, const float* __restrict__ Gws,
    const float* __restrict__ b2, float* __restrict__ out) {
    __shared__ float4 abc[Mm];  // (v*c0, v*c1, v, 0)
    int tile = blockIdx.x >> 1, kh = blockIdx.x & 1;
    int b = tile >> 6, tt = tile & 63;
    int t = threadIdx.x;
    if (t < Mm) {
        int m = t;
        float2 c = *(const float2*)&coords[((size_t)(b * Mm + m) * Tt + tt) * 2];
        float v = vis[(b * Mm + m) * Tt + tt];
        float c0 = c.x, c1 = c.y;
        if (isnan(c0)) { v = 0.f; c0 = 0.f; }
        if (isnan(c1)) c1 = 0.f;
        abc[m] = make_float4(v * c0, v * c1, v, 0.f);
    }
    __syncthreads();
    int k = kh * 384 + t;
    float p0 = 0.f, p1 = 0.f, pu = 0.f;
#pragma unroll 4
    for (int n = 0; n < Mm; ++n) {
        float4 a = abc[n];
        float qe = Qws[(size_t)(2 * n) * DO + k];
        float qo = Qws[(size_t)(2 * n) * DO + DO + k];
        p0 += a.z * qe; p1 += a.z * qo;
        pu += a.x * qe + a.y * qo;
    }
    float pq = Qws[(size_t)512 * DO + k] + b2[k];   // b1@w2_top + fc_out_b
    size_t ob = (size_t)tile * OUT_TILE + k;
#pragma unroll 2
    for (int m = 0; m < Mm; ++m) {
        float4 a = abc[m];
        float g = Gws[m * DO + k];
        out[ob + (size_t)m * DO] = g + pq + a.x * p0 + a.y * p1 - a.z * pu;
    }
}

// ========================== FALLBACK (R4, passing) ==========================
template <int TO_OUT>
__global__ void k_G(const float* __restrict__ pos, const float* __restrict__ w2,
                    const float* __restrict__ b1, const float* __restrict__ b2,
                    float* __restrict__ Gws, float* __restrict__ outg) {
    __shared__ float posT[DM * 4];
    __shared__ float b1s[DM];
    int mg = blockIdx.x >> 2, ks = blockIdx.x & 3;
    int t = threadIdx.x;
    for (int idx = t; idx < DM * 4; idx += 192)
        posT[idx] = pos[(mg * 4 + (idx & 3)) * DM + (idx >> 2)];
    for (int idx = t; idx < DM; idx += 192) b1s[idx] = b1[idx];
    __syncthreads();
    int k = ks * 192 + t;
    float pb = b2[k];
#pragma unroll 4
    for (int j = 0; j < DM; ++j) pb += b1s[j] * w2[j * DO + k];
    float a0 = pb, a1 = pb, a2 = pb, a3 = pb;
#pragma unroll 4
    for (int j = 0; j < DM; ++j) {
        float w = w2[(DM + j) * DO + k];
        float4 q = *(const float4*)&posT[j * 4];
        a0 += q.x * w; a1 += q.y * w; a2 += q.z * w; a3 += q.w * w;
    }
    if (TO_OUT) {
        for (int tile = 0; tile < 256; ++tile) {
            size_t base = (size_t)tile * OUT_TILE + (size_t)(mg * 4) * DO + k;
            outg[base + 0 * DO] = a0; outg[base + 1 * DO] = a1;
            outg[base + 2 * DO] = a2; outg[base + 3 * DO] = a3;
        }
    } else {
        Gws[(mg * 4 + 0) * DO + k] = a0; Gws[(mg * 4 + 1) * DO + k] = a1;
        Gws[(mg * 4 + 2) * DO + k] = a2; Gws[(mg * 4 + 3) * DO + k] = a3;
    }
}

template <int G_FROM_OUT>
__global__ void k_main(const float* __restrict__ coords, const float* __restrict__ vis,
                       const float* __restrict__ w1, const float* __restrict__ w2,
                       const float* __restrict__ Gws, float* __restrict__ out) {
    __shared__ float4 abc[Mm];
    __shared__ float s0s[DM], s1s[DM], uus[DM];
    int tile = blockIdx.x;
    int b = tile >> 6, tt = tile & 63;
    int t = threadIdx.x;
    if (t < Mm) {
        int m = t;
        float2 c = *(const float2*)&coords[((size_t)(b * Mm + m) * Tt + tt) * 2];
        float v = vis[(b * Mm + m) * Tt + tt];
        float c0 = c.x, c1 = c.y;
        if (isnan(c0)) { v = 0.f; c0 = 0.f; }
        if (isnan(c1)) c1 = 0.f;
        abc[m] = make_float4(v * c0, v * c1, v, 0.f);
    }
    __syncthreads();
    if (t < DM) {
        int j = t;
        float s0 = 0.f, s1 = 0.f, uu = 0.f;
#pragma unroll 4
        for (int n = 0; n < Mm; ++n) {
            float4 a = abc[n];
            float w0 = w1[(2 * n) * DM + j];
            float wv = w1[(2 * n + 1) * DM + j];
            s0 += a.z * w0; s1 += a.z * wv; uu += a.x * w0 + a.y * wv;
        }
        s0s[j] = s0; s1s[j] = s1; uus[j] = uu;
    }
    __syncthreads();
    int k = t;
    float p0 = 0.f, p1 = 0.f, pu = 0.f;
#pragma unroll 4
    for (int j = 0; j < DM; ++j) {
        float w = w2[j * DO + k];
        p0 += s0s[j] * w; p1 += s1s[j] * w; pu += uus[j] * w;
    }
    size_t ob = (size_t)tile * OUT_TILE + k;
#pragma unroll 2
    for (int m = 0; m < Mm; ++m) {
        float4 a = abc[m];
        float g = G_FROM_OUT ? out[ob + (size_t)m * DO] : Gws[m * DO + k];
        out[ob + (size_t)m * DO] = g + a.x * p0 + a.y * p1 - a.z * pu;
    }
}

// ---------------------------------------------------------------------------
extern "C" void kernel_launch(void* const* d_in, const int* in_sizes, int n_in,
                              void* d_out, int out_size, void* d_ws, size_t ws_size,
                              hipStream_t stream) {
    const float* coords = (const float*)d_in[0];
    const float* vis    = (const float*)d_in[1];
    const float* pos    = (const float*)d_in[2];
    const float* w1     = (const float*)d_in[3];
    const float* b1     = (const float*)d_in[4];
    const float* w2     = (const float*)d_in[5];
    const float* b2     = (const float*)d_in[6];
    float* out = (float*)d_out;
    float* ws  = (float*)d_ws;

    const size_t need_fast = (WS_G + (size_t)Mm * DO) * sizeof(float);  // 2.36 MB
    if (ws_size >= need_fast) {
        float* Qws = ws;
        float* Gws = ws + WS_G;
        k_gemm<<<dim3(12, 13), dim3(256), 0, stream>>>(w1, b1, pos, w2, Qws, Gws);
        k_epi <<<dim3(512),    dim3(384), 0, stream>>>(coords, vis, Qws, Gws, b2, out);
    } else if (ws_size >= (size_t)Mm * DO * sizeof(float)) {
        k_G<0>   <<<dim3(256), dim3(192), 0, stream>>>(pos, w2, b1, b2, ws, nullptr);
        k_main<0><<<dim3(256), dim3(768), 0, stream>>>(coords, vis, w1, w2, ws, out);
    } else {
        k_G<1>   <<<dim3(256), dim3(192), 0, stream>>>(pos, w2, b1, b2, nullptr, out);
        k_main<1><<<dim3(256), dim3(768), 0, stream>>>(coords, vis, w1, w2, nullptr, out);
    }
}